// Round 1
// baseline (632.436 us; speedup 1.0000x reference)
//
#include <hip/hip_runtime.h>
#include <math.h>

#define NN 50000
#define NE 800000
#define HD 128

// ---------------- edge histogram: deg + sum_ea ----------------
__global__ void k_edge_count(const int* __restrict__ ei, const float* __restrict__ ew,
                             int* __restrict__ deg, float* __restrict__ sum_ea) {
    int e = blockIdx.x * blockDim.x + threadIdx.x;
    if (e >= NE) return;
    int d = ei[NE + e];
    atomicAdd(&deg[d], 1);
    atomicAdd(&sum_ea[d], ew[e]);
}

// ---------------- loop_ea = sum_ea / max(deg,1) ----------------
__global__ void k_loop_ea(const int* __restrict__ deg, const float* __restrict__ sum_ea,
                          float* __restrict__ loop_ea) {
    int v = blockIdx.x * blockDim.x + threadIdx.x;
    if (v >= NN) return;
    loop_ea[v] = sum_ea[v] / fmaxf((float)deg[v], 1.0f);
}

// ---------------- 2-level exclusive scan of deg -> offs ----------------
__global__ void k_scan1(const int* __restrict__ deg, int* __restrict__ offs,
                        int* __restrict__ bsums) {
    __shared__ int sh[256];
    int t = threadIdx.x;
    int i = blockIdx.x * 256 + t;
    int v = (i < NN) ? deg[i] : 0;
    sh[t] = v;
    __syncthreads();
    for (int off = 1; off < 256; off <<= 1) {
        int x = (t >= off) ? sh[t - off] : 0;
        __syncthreads();
        sh[t] += x;
        __syncthreads();
    }
    if (i < NN) offs[i] = sh[t] - v;          // exclusive within block
    if (t == 255) bsums[blockIdx.x] = sh[255]; // block total
}

__global__ void k_scan2(int* __restrict__ bsums, int nb) {
    __shared__ int sh[256];
    int t = threadIdx.x;
    int v = (t < nb) ? bsums[t] : 0;
    sh[t] = v;
    __syncthreads();
    for (int off = 1; off < 256; off <<= 1) {
        int x = (t >= off) ? sh[t - off] : 0;
        __syncthreads();
        sh[t] += x;
        __syncthreads();
    }
    if (t < nb) bsums[t] = sh[t] - v;          // exclusive block offsets
}

__global__ void k_scan3(int* __restrict__ offs, const int* __restrict__ bsums) {
    int i = blockIdx.x * 256 + threadIdx.x;
    if (i == 0) offs[NN] = NE;
    if (i >= NN) return;
    offs[i] += bsums[blockIdx.x];
}

// ---------------- CSR scatter ----------------
__global__ void k_csr_fill(const int* __restrict__ ei, const float* __restrict__ ew,
                           const int* __restrict__ offs, int* __restrict__ cursor,
                           int* __restrict__ csr_src, float* __restrict__ csr_ea) {
    int e = blockIdx.x * blockDim.x + threadIdx.x;
    if (e >= NE) return;
    int s = ei[e];
    int d = ei[NE + e];
    int pos = offs[d] + atomicAdd(&cursor[d], 1);
    csr_src[pos] = s;
    csr_ea[pos] = ew[e];
}

// ---------------- dual GEMM: outl = A@Wl + bl, outr = A@Wr + br ----------------
// A: n x 128 row-major, W: 128 x 128 row-major.
// Block: 256 threads, 32 rows per block. col = t&127, row-group = t>>7.
__global__ __launch_bounds__(256) void k_gemm_dual(
        const float* __restrict__ A,
        const float* __restrict__ Wl, const float* __restrict__ bl,
        const float* __restrict__ Wr, const float* __restrict__ br,
        float* __restrict__ outl, float* __restrict__ outr) {
    __shared__ float Ash[32 * 128];
    int t = threadIdx.x;
    int col = t & 127;
    int rg = t >> 7;
    int rowbase = blockIdx.x * 32;
    for (int idx = t; idx < 32 * 128; idx += 256) {
        int r = rowbase + (idx >> 7);
        Ash[idx] = (r < NN) ? A[r * HD + (idx & 127)] : 0.f;
    }
    __syncthreads();
    float accl[16], accr[16];
#pragma unroll
    for (int i = 0; i < 16; ++i) { accl[i] = 0.f; accr[i] = 0.f; }
#pragma unroll 4
    for (int k = 0; k < 128; ++k) {
        float wl = Wl[k * HD + col];
        float wr = Wr[k * HD + col];
#pragma unroll
        for (int i = 0; i < 16; ++i) {
            float a = Ash[(rg + 2 * i) * HD + k];
            accl[i] = fmaf(a, wl, accl[i]);
            accr[i] = fmaf(a, wr, accr[i]);
        }
    }
    float bll = bl[col], brr = br[col];
#pragma unroll
    for (int i = 0; i < 16; ++i) {
        int r = rowbase + rg + 2 * i;
        if (r < NN) {
            outl[r * HD + col] = accl[i] + bll;
            outr[r * HD + col] = accr[i] + brr;
        }
    }
}

// ---------------- fused per-node GATv2 sweep (online softmax) ----------------
// One 64-lane wave per node; lane handles channels 2l, 2l+1.
// Head of channel c is c>>5; lanes [16h,16h+16) form head h, so shfl_xor 1/2/4/8
// reduces within a head.
template <bool PRELU>
__global__ __launch_bounds__(256) void k_node(
        const float* __restrict__ xl, const float* __restrict__ xr,
        const int* __restrict__ offs, const int* __restrict__ csr_src,
        const float* __restrict__ csr_ea, const float* __restrict__ loop_ea,
        const float* __restrict__ We, const float* __restrict__ att,
        const float* __restrict__ bias, const float* __restrict__ prelu,
        float* __restrict__ out) {
    int wid = (blockIdx.x * blockDim.x + threadIdx.x) >> 6;
    int lane = threadIdx.x & 63;
    if (wid >= NN) return;
    int v = wid;
    int c0 = lane << 1;

    float2 xrv = *(const float2*)&xr[v * HD + c0];
    float we0 = We[c0], we1 = We[c0 + 1];
    float a0 = att[c0], a1 = att[c0 + 1];   // att is (H,C) flat = channel-indexed

    float m = -INFINITY, s = 0.f, o0 = 0.f, o1 = 0.f;
    int beg = offs[v], end = offs[v + 1];
    for (int e = beg; e <= end; ++e) {
        int src;
        float w;
        if (e < end) {
            src = csr_src[e];
            w = csr_ea[e];
        } else {            // self loop
            src = v;
            w = loop_ea[v];
        }
        float2 xls = *(const float2*)&xl[src * HD + c0];
        float t0 = xls.x + xrv.x + w * we0;
        t0 = (t0 >= 0.f) ? t0 : 0.2f * t0;
        float t1 = xls.y + xrv.y + w * we1;
        t1 = (t1 >= 0.f) ? t1 : 0.2f * t1;
        float part = a0 * t0 + a1 * t1;
        part += __shfl_xor(part, 1);
        part += __shfl_xor(part, 2);
        part += __shfl_xor(part, 4);
        part += __shfl_xor(part, 8);
        float newm = fmaxf(m, part);
        float scale = __expf(m - newm);     // first iter: exp(-inf) = 0
        float p = __expf(part - newm);
        s = s * scale + p;
        o0 = fmaf(o0, scale, p * xls.x);
        o1 = fmaf(o1, scale, p * xls.y);
        m = newm;
    }
    float inv = 1.f / s;
    float r0 = o0 * inv + bias[c0];
    float r1 = o1 * inv + bias[c0 + 1];
    if (PRELU) {
        float a = *prelu;
        r0 = (r0 >= 0.f) ? r0 : a * r0;
        r1 = (r1 >= 0.f) ? r1 : a * r1;
    }
    *(float2*)&out[v * HD + c0] = make_float2(r0, r1);
}

// ---------------- launch ----------------
extern "C" void kernel_launch(void* const* d_in, const int* in_sizes, int n_in,
                              void* d_out, int out_size, void* d_ws, size_t ws_size,
                              hipStream_t stream) {
    const float* x    = (const float*)d_in[0];
    const int*   ei   = (const int*)d_in[1];
    const float* ew   = (const float*)d_in[2];
    const float* Wl0  = (const float*)d_in[3];
    const float* bl0  = (const float*)d_in[4];
    const float* Wr0  = (const float*)d_in[5];
    const float* br0  = (const float*)d_in[6];
    const float* We0  = (const float*)d_in[7];
    const float* att0 = (const float*)d_in[8];
    const float* b0   = (const float*)d_in[9];
    const float* Wl1  = (const float*)d_in[10];
    const float* bl1  = (const float*)d_in[11];
    const float* Wr1  = (const float*)d_in[12];
    const float* br1  = (const float*)d_in[13];
    const float* We1  = (const float*)d_in[14];
    const float* att1 = (const float*)d_in[15];
    const float* b1   = (const float*)d_in[16];
    const float* prelu= (const float*)d_in[17];
    float* out = (float*)d_out;

    char* ws = (char*)d_ws;
    size_t off = 0;
    auto alloc = [&](size_t bytes) {
        char* p = ws + off;
        off += (bytes + 255) & ~size_t(255);
        return p;
    };
    float* bufA   = (float*)alloc(sizeof(float) * NN * HD); // xl
    float* bufB   = (float*)alloc(sizeof(float) * NN * HD); // xr
    float* bufH   = (float*)alloc(sizeof(float) * NN * HD); // layer-0 output
    int*   deg    = (int*)alloc(sizeof(int) * NN);
    float* sum_ea = (float*)alloc(sizeof(float) * NN);
    float* loop_ea= (float*)alloc(sizeof(float) * NN);
    int*   offs   = (int*)alloc(sizeof(int) * (NN + 1));
    int*   cursor = (int*)alloc(sizeof(int) * NN);
    int*   bsums  = (int*)alloc(sizeof(int) * 256);
    int*   csr_src= (int*)alloc(sizeof(int) * NE);
    float* csr_ea = (float*)alloc(sizeof(float) * NE);
    (void)ws_size; (void)in_sizes; (void)n_in; (void)out_size;

    hipMemsetAsync(deg, 0, sizeof(int) * NN, stream);
    hipMemsetAsync(sum_ea, 0, sizeof(float) * NN, stream);
    hipMemsetAsync(cursor, 0, sizeof(int) * NN, stream);

    const int EB = (NE + 255) / 256;
    const int NB = (NN + 255) / 256;   // 196

    k_edge_count<<<EB, 256, 0, stream>>>(ei, ew, deg, sum_ea);
    k_loop_ea<<<NB, 256, 0, stream>>>(deg, sum_ea, loop_ea);
    k_scan1<<<NB, 256, 0, stream>>>(deg, offs, bsums);
    k_scan2<<<1, 256, 0, stream>>>(bsums, NB);
    k_scan3<<<NB, 256, 0, stream>>>(offs, bsums);
    k_csr_fill<<<EB, 256, 0, stream>>>(ei, ew, offs, cursor, csr_src, csr_ea);

    const int GB = (NN + 31) / 32;     // gemm blocks
    const int VB = (NN * 64 + 255) / 256; // node-wave blocks

    // layer 0
    k_gemm_dual<<<GB, 256, 0, stream>>>(x, Wl0, bl0, Wr0, br0, bufA, bufB);
    k_node<true><<<VB, 256, 0, stream>>>(bufA, bufB, offs, csr_src, csr_ea, loop_ea,
                                         We0, att0, b0, prelu, bufH);
    // layer 1
    k_gemm_dual<<<GB, 256, 0, stream>>>(bufH, Wl1, bl1, Wr1, br1, bufA, bufB);
    k_node<false><<<VB, 256, 0, stream>>>(bufA, bufB, offs, csr_src, csr_ea, loop_ea,
                                          We1, att1, b1, nullptr, out);
}

// Round 2
// 512.327 us; speedup vs baseline: 1.2344x; 1.2344x over previous
//
#include <hip/hip_runtime.h>
#include <math.h>

#define NN 50000
#define NE 800000
#define HD 128

// ---------------- edge histogram: deg + sum_ea ----------------
__global__ void k_edge_count(const int* __restrict__ ei, const float* __restrict__ ew,
                             int* __restrict__ deg, float* __restrict__ sum_ea) {
    int e = blockIdx.x * blockDim.x + threadIdx.x;
    if (e >= NE) return;
    int d = ei[NE + e];
    atomicAdd(&deg[d], 1);
    atomicAdd(&sum_ea[d], ew[e]);
}

// ---------------- loop_ea = sum_ea / max(deg,1) ----------------
__global__ void k_loop_ea(const int* __restrict__ deg, const float* __restrict__ sum_ea,
                          float* __restrict__ loop_ea) {
    int v = blockIdx.x * blockDim.x + threadIdx.x;
    if (v >= NN) return;
    loop_ea[v] = sum_ea[v] / fmaxf((float)deg[v], 1.0f);
}

// ---------------- 2-level exclusive scan of deg -> offs ----------------
__global__ void k_scan1(const int* __restrict__ deg, int* __restrict__ offs,
                        int* __restrict__ bsums) {
    __shared__ int sh[256];
    int t = threadIdx.x;
    int i = blockIdx.x * 256 + t;
    int v = (i < NN) ? deg[i] : 0;
    sh[t] = v;
    __syncthreads();
    for (int off = 1; off < 256; off <<= 1) {
        int x = (t >= off) ? sh[t - off] : 0;
        __syncthreads();
        sh[t] += x;
        __syncthreads();
    }
    if (i < NN) offs[i] = sh[t] - v;          // exclusive within block
    if (t == 255) bsums[blockIdx.x] = sh[255]; // block total
}

__global__ void k_scan2(int* __restrict__ bsums, int nb) {
    __shared__ int sh[256];
    int t = threadIdx.x;
    int v = (t < nb) ? bsums[t] : 0;
    sh[t] = v;
    __syncthreads();
    for (int off = 1; off < 256; off <<= 1) {
        int x = (t >= off) ? sh[t - off] : 0;
        __syncthreads();
        sh[t] += x;
        __syncthreads();
    }
    if (t < nb) bsums[t] = sh[t] - v;          // exclusive block offsets
}

__global__ void k_scan3(int* __restrict__ offs, const int* __restrict__ bsums) {
    int i = blockIdx.x * 256 + threadIdx.x;
    if (i == 0) offs[NN] = NE;
    if (i >= NN) return;
    offs[i] += bsums[blockIdx.x];
}

// ---------------- CSR scatter: {src, weight} packed ----------------
__global__ void k_csr_fill(const int* __restrict__ ei, const float* __restrict__ ew,
                           const int* __restrict__ offs, int* __restrict__ cursor,
                           int2* __restrict__ csr) {
    int e = blockIdx.x * blockDim.x + threadIdx.x;
    if (e >= NE) return;
    int s = ei[e];
    int d = ei[NE + e];
    int pos = offs[d] + atomicAdd(&cursor[d], 1);
    csr[pos] = make_int2(s, __float_as_int(ew[e]));
}

// ---------------- dual GEMM: outl = A@Wl + bl, outr = A@Wr + br ----------------
__global__ __launch_bounds__(256) void k_gemm_dual(
        const float* __restrict__ A,
        const float* __restrict__ Wl, const float* __restrict__ bl,
        const float* __restrict__ Wr, const float* __restrict__ br,
        float* __restrict__ outl, float* __restrict__ outr) {
    __shared__ float Ash[32 * 128];
    int t = threadIdx.x;
    int col = t & 127;
    int rg = t >> 7;
    int rowbase = blockIdx.x * 32;
    for (int idx = t; idx < 32 * 128; idx += 256) {
        int r = rowbase + (idx >> 7);
        Ash[idx] = (r < NN) ? A[r * HD + (idx & 127)] : 0.f;
    }
    __syncthreads();
    float accl[16], accr[16];
#pragma unroll
    for (int i = 0; i < 16; ++i) { accl[i] = 0.f; accr[i] = 0.f; }
#pragma unroll 4
    for (int k = 0; k < 128; ++k) {
        float wl = Wl[k * HD + col];
        float wr = Wr[k * HD + col];
#pragma unroll
        for (int i = 0; i < 16; ++i) {
            float a = Ash[(rg + 2 * i) * HD + k];
            accl[i] = fmaf(a, wl, accl[i]);
            accr[i] = fmaf(a, wr, accr[i]);
        }
    }
    float bll = bl[col], brr = br[col];
#pragma unroll
    for (int i = 0; i < 16; ++i) {
        int r = rowbase + rg + 2 * i;
        if (r < NN) {
            outl[r * HD + col] = accl[i] + bll;
            outr[r * HD + col] = accr[i] + brr;
        }
    }
}

// ---------------- fused per-node GATv2 sweep ----------------
// One wave per node, split into 4 independent 16-lane subgroups, each with its
// own online-softmax state over a strided quarter of the edges; states merged
// at the end (online softmax is associative). Lane j owns channels [8j,8j+8).
// Head h = j>>2 (8 contiguous channels stay within one 32-ch head), so the
// att-dot reduce is shfl_xor 1,2 within the 4-lane head group.
#define MNEG (-1e30f)

__device__ __forceinline__ void load8(const float* __restrict__ p, float* r) {
    float4 t0 = *(const float4*)p;
    float4 t1 = *(const float4*)(p + 4);
    r[0] = t0.x; r[1] = t0.y; r[2] = t0.z; r[3] = t0.w;
    r[4] = t1.x; r[5] = t1.y; r[6] = t1.z; r[7] = t1.w;
}

template <bool PRELU>
__global__ __launch_bounds__(256) void k_node(
        const float* __restrict__ xl, const float* __restrict__ xr,
        const int* __restrict__ offs, const int2* __restrict__ csr,
        const float* __restrict__ loop_ea,
        const float* __restrict__ We, const float* __restrict__ att,
        const float* __restrict__ bias, const float* __restrict__ prelu,
        float* __restrict__ out) {
    int wid = (blockIdx.x * blockDim.x + threadIdx.x) >> 6;
    if (wid >= NN) return;
    const int lane = threadIdx.x & 63;
    const int g = lane >> 4;        // subgroup 0..3
    const int j = lane & 15;        // lane in subgroup
    const int c0 = j << 3;          // first of 8 owned channels
    const int v = wid;

    float xrv[8], wev[8], atv[8];
    load8(&xr[(size_t)v * HD + c0], xrv);
    load8(&We[c0], wev);
    load8(&att[c0], atv);

    const int beg = offs[v];
    const int deg = offs[v + 1] - beg;     // item indices 0..deg; item deg = self loop
    const float lea = loop_ea[v];
    const int2 selfe = make_int2(v, __float_as_int(lea));

    float m = MNEG, s = 0.f;
    float o[8];
#pragma unroll
    for (int k = 0; k < 8; ++k) o[k] = 0.f;

#define DOT(xv, part)                                            \
    {                                                            \
        part = 0.f;                                              \
        _Pragma("unroll") for (int k = 0; k < 8; ++k) {          \
            float tc = xv[k] + xrv[k] + w##xv * wev[k];          \
            tc = (tc >= 0.f) ? tc : 0.2f * tc;                   \
            part = fmaf(atv[k], tc, part);                       \
        }                                                        \
        part += __shfl_xor(part, 1);                             \
        part += __shfl_xor(part, 2);                             \
    }

#define UPDATE(part, xv)                                         \
    {                                                            \
        float newm = fmaxf(m, part);                             \
        float sc = __expf(m - newm);                             \
        float p = __expf(part - newm);                           \
        s = fmaf(s, sc, p);                                      \
        _Pragma("unroll") for (int k = 0; k < 8; ++k)            \
            o[k] = fmaf(o[k], sc, p * xv[k]);                    \
        m = newm;                                                \
    }

    int i = g;
    // pair-unrolled: two independent gathers in flight per step
    for (; i + 4 <= deg; i += 8) {
        int2 e0 = csr[beg + i];                       // i < deg guaranteed
        int2 e1 = (i + 4 < deg) ? csr[beg + i + 4] : selfe;
        int s0 = e0.x; float wxv0 = __int_as_float(e0.y);
        int s1 = e1.x; float wxv1 = __int_as_float(e1.y);
        float xv0[8], xv1[8];
        load8(&xl[(size_t)s0 * HD + c0], xv0);
        load8(&xl[(size_t)s1 * HD + c0], xv1);
        float p0, p1;
        DOT(xv0, p0)
        DOT(xv1, p1)
        UPDATE(p0, xv0)
        UPDATE(p1, xv1)
    }
    if (i <= deg) {
        int2 e0 = (i < deg) ? csr[beg + i] : selfe;
        int s0 = e0.x; float wxv0 = __int_as_float(e0.y);
        float xv0[8];
        load8(&xl[(size_t)s0 * HD + c0], xv0);
        float p0;
        DOT(xv0, p0)
        UPDATE(p0, xv0)
    }
#undef DOT
#undef UPDATE

    // merge the 4 subgroup states (butterfly across lanes j, j^16, j^32)
#pragma unroll
    for (int d = 16; d < 64; d <<= 1) {
        float m2 = __shfl_xor(m, d);
        float s2 = __shfl_xor(s, d);
        float M = fmaxf(m, m2);
        float a = __expf(m - M);
        float b2 = __expf(m2 - M);
        s = s * a + s2 * b2;
#pragma unroll
        for (int k = 0; k < 8; ++k) {
            float o2 = __shfl_xor(o[k], d);
            o[k] = o[k] * a + o2 * b2;
        }
        m = M;
    }

    if (g == 0) {
        float bi[8];
        load8(&bias[c0], bi);
        float inv = 1.f / s;
        float r[8];
#pragma unroll
        for (int k = 0; k < 8; ++k) r[k] = fmaf(o[k], inv, bi[k]);
        if (PRELU) {
            float a = *prelu;
#pragma unroll
            for (int k = 0; k < 8; ++k) r[k] = (r[k] >= 0.f) ? r[k] : a * r[k];
        }
        float* op = &out[(size_t)v * HD + c0];
        *(float4*)op = make_float4(r[0], r[1], r[2], r[3]);
        *(float4*)(op + 4) = make_float4(r[4], r[5], r[6], r[7]);
    }
}

// ---------------- launch ----------------
extern "C" void kernel_launch(void* const* d_in, const int* in_sizes, int n_in,
                              void* d_out, int out_size, void* d_ws, size_t ws_size,
                              hipStream_t stream) {
    const float* x    = (const float*)d_in[0];
    const int*   ei   = (const int*)d_in[1];
    const float* ew   = (const float*)d_in[2];
    const float* Wl0  = (const float*)d_in[3];
    const float* bl0  = (const float*)d_in[4];
    const float* Wr0  = (const float*)d_in[5];
    const float* br0  = (const float*)d_in[6];
    const float* We0  = (const float*)d_in[7];
    const float* att0 = (const float*)d_in[8];
    const float* b0   = (const float*)d_in[9];
    const float* Wl1  = (const float*)d_in[10];
    const float* bl1  = (const float*)d_in[11];
    const float* Wr1  = (const float*)d_in[12];
    const float* br1  = (const float*)d_in[13];
    const float* We1  = (const float*)d_in[14];
    const float* att1 = (const float*)d_in[15];
    const float* b1   = (const float*)d_in[16];
    const float* prelu= (const float*)d_in[17];
    float* out = (float*)d_out;

    char* ws = (char*)d_ws;
    size_t off = 0;
    auto alloc = [&](size_t bytes) {
        char* p = ws + off;
        off += (bytes + 255) & ~size_t(255);
        return p;
    };
    float* bufA   = (float*)alloc(sizeof(float) * NN * HD); // xl
    float* bufB   = (float*)alloc(sizeof(float) * NN * HD); // xr
    float* bufH   = (float*)alloc(sizeof(float) * NN * HD); // layer-0 output
    int*   deg    = (int*)alloc(sizeof(int) * NN);
    float* sum_ea = (float*)alloc(sizeof(float) * NN);
    float* loop_ea= (float*)alloc(sizeof(float) * NN);
    int*   offs   = (int*)alloc(sizeof(int) * (NN + 1));
    int*   cursor = (int*)alloc(sizeof(int) * NN);
    int*   bsums  = (int*)alloc(sizeof(int) * 256);
    int2*  csr    = (int2*)alloc(sizeof(int2) * NE);
    (void)ws_size; (void)in_sizes; (void)n_in; (void)out_size;

    hipMemsetAsync(deg, 0, sizeof(int) * NN, stream);
    hipMemsetAsync(sum_ea, 0, sizeof(float) * NN, stream);
    hipMemsetAsync(cursor, 0, sizeof(int) * NN, stream);

    const int EB = (NE + 255) / 256;
    const int NB = (NN + 255) / 256;

    k_edge_count<<<EB, 256, 0, stream>>>(ei, ew, deg, sum_ea);
    k_loop_ea<<<NB, 256, 0, stream>>>(deg, sum_ea, loop_ea);
    k_scan1<<<NB, 256, 0, stream>>>(deg, offs, bsums);
    k_scan2<<<1, 256, 0, stream>>>(bsums, NB);
    k_scan3<<<NB, 256, 0, stream>>>(offs, bsums);
    k_csr_fill<<<EB, 256, 0, stream>>>(ei, ew, offs, cursor, csr);

    const int GB = (NN + 31) / 32;
    const int VB = (NN * 64 + 255) / 256;

    // layer 0
    k_gemm_dual<<<GB, 256, 0, stream>>>(x, Wl0, bl0, Wr0, br0, bufA, bufB);
    k_node<true><<<VB, 256, 0, stream>>>(bufA, bufB, offs, csr, loop_ea,
                                         We0, att0, b0, prelu, bufH);
    // layer 1
    k_gemm_dual<<<GB, 256, 0, stream>>>(bufH, Wl1, bl1, Wr1, br1, bufA, bufB);
    k_node<false><<<VB, 256, 0, stream>>>(bufA, bufB, offs, csr, loop_ea,
                                          We1, att1, b1, nullptr, out);
}